// Round 1
// baseline (44.369 us; speedup 1.0000x reference)
//
#include <hip/hip_runtime.h>

// RoiPooling: img [B,32,32,256] f32, rois [B,64,4] f32 (x,y,w,h)
// Output [B, R, 21*C]; bins: level1 (1) + level2 (4, ix*2+jy) + level4 (16, ix*4+jy).
// Key fact: level-1/2 bin boundaries coincide bit-exactly with even level-4
// boundaries (k*(h/4) is an exact pow2 scaling), so we pool only the 4x4 grid
// and reduce.  jnp.round == round-half-to-even == __float2int_rn.

#define IMG_H 32
#define IMG_W 32
#define NCH   256

__global__ __launch_bounds__(256) void roi_pool_kernel(
    const float* __restrict__ img,   // [B, H, W, C]
    const float* __restrict__ rois,  // [B*R, 4]
    float* __restrict__ out)         // [B*R, 21, C]
{
    const int br = blockIdx.x;        // b*R + r
    const int b  = br >> 6;           // R = 64
    const int c  = threadIdx.x;       // channel

    const float4 roi = *reinterpret_cast<const float4*>(rois + (size_t)br * 4);
    const float x = roi.x, y = roi.y, w = roi.z, h = roi.w;

    // Level-4 boundaries.  Column bins come from (x, h); row bins from (y, w)
    // (axis swap faithful to the reference).
    const float hq = h * 0.25f;   // == h/4 exactly
    const float wq = w * 0.25f;
    int cb[5], rb[5];
#pragma unroll
    for (int k = 0; k <= 4; ++k) {
        cb[k] = __float2int_rn(x + (float)k * hq);
        rb[k] = __float2int_rn(y + (float)k * wq);
    }

    const float NEG = -__builtin_inff();
    float P[4][4];   // [ix][jy], fully static indexing
#pragma unroll
    for (int i = 0; i < 4; ++i)
#pragma unroll
        for (int j = 0; j < 4; ++j) P[i][j] = NEG;

    const float* imgb = img + (size_t)b * IMG_H * IMG_W * NCH + c;

#pragma unroll
    for (int jy = 0; jy < 4; ++jy) {
        const int r0 = max(rb[jy], 0);
        const int r1 = min(rb[jy + 1], IMG_H);
        for (int row = r0; row < r1; ++row) {
            const float* rowp = imgb + (size_t)row * (IMG_W * NCH);
#pragma unroll
            for (int ix = 0; ix < 4; ++ix) {
                const int c0 = max(cb[ix], 0);
                const int c1 = min(cb[ix + 1], IMG_W);
                float m = P[ix][jy];
                for (int col = c0; col < c1; ++col) {
                    m = fmaxf(m, rowp[(size_t)col * NCH]);
                }
                P[ix][jy] = m;
            }
        }
    }

    float* ob = out + (size_t)br * 21 * NCH + c;

    // level 4: bins 5..20, index 5 + ix*4 + jy
#pragma unroll
    for (int ix = 0; ix < 4; ++ix)
#pragma unroll
        for (int jy = 0; jy < 4; ++jy)
            ob[(size_t)(5 + ix * 4 + jy) * NCH] = P[ix][jy];

    // level 2: bins 1..4, index 1 + ix*2 + jy  (each = max of 2x2 level-4 bins)
    float l1 = NEG;
#pragma unroll
    for (int ix = 0; ix < 2; ++ix)
#pragma unroll
        for (int jy = 0; jy < 2; ++jy) {
            const float m = fmaxf(
                fmaxf(P[2 * ix][2 * jy],     P[2 * ix][2 * jy + 1]),
                fmaxf(P[2 * ix + 1][2 * jy], P[2 * ix + 1][2 * jy + 1]));
            ob[(size_t)(1 + ix * 2 + jy) * NCH] = m;
            l1 = fmaxf(l1, m);
        }

    // level 1: bin 0
    ob[0] = l1;
}

extern "C" void kernel_launch(void* const* d_in, const int* in_sizes, int n_in,
                              void* d_out, int out_size, void* d_ws, size_t ws_size,
                              hipStream_t stream) {
    const float* img  = (const float*)d_in[0];
    const float* rois = (const float*)d_in[1];
    float* out = (float*)d_out;

    const int n_rois = in_sizes[1] / 4;   // B * R = 256
    roi_pool_kernel<<<n_rois, NCH, 0, stream>>>(img, rois, out);
}

// Round 2
// 11.542 us; speedup vs baseline: 3.8441x; 3.8441x over previous
//
#include <hip/hip_runtime.h>

// RoiPooling: img [B,32,32,256] f32, rois [B,64,4] f32 (x,y,w,h)
// Out [B*R, 21, 256]; bin order: 0 = level1, 1..4 = level2 (i*2+j),
// 5..20 = level4 (ix*4+jy).
// Level-1/2 boundaries bit-match even level-4 boundaries (k*(h/4) pow2-exact),
// so only the 4x4 level-4 grid is pooled from pixels; coarser levels reduce it.
// jnp.round == round-half-to-even == __float2int_rn.
//
// Parallel decomposition (vs R1's 1 thread = 1 channel = whole ROI):
//   block = 1024 threads = c4(64 float4-groups) x ix(4) x jy(4), grid = B*R.
//   Each thread pools ONE level-4 bin for 4 channels -> ~12 float4 loads,
//   16 waves/CU instead of 4, 1 KB per wave load instr.

#define IMG_H 32
#define IMG_W 32
#define NCH   256

static __device__ __forceinline__ float4 fmax4(float4 a, float4 b) {
    return make_float4(fmaxf(a.x, b.x), fmaxf(a.y, b.y),
                       fmaxf(a.z, b.z), fmaxf(a.w, b.w));
}

__global__ __launch_bounds__(1024) void roi_pool_kernel(
    const float* __restrict__ img,   // [B, H, W, C]
    const float* __restrict__ rois,  // [B*R, 4]
    float* __restrict__ out)         // [B*R, 21, C]
{
    const int br  = blockIdx.x;       // b*R + r
    const int b   = br >> 6;          // R = 64
    const int tid = threadIdx.x;
    const int c4  = tid & 63;         // float4 channel group: channels 4*c4..4*c4+3
    const int ix  = (tid >> 6) & 3;   // column bin
    const int jy  = tid >> 8;         // row bin

    const float4 roi = *reinterpret_cast<const float4*>(rois + (size_t)br * 4);
    const float x = roi.x, y = roi.y, w = roi.z, h = roi.w;

    // Column bins from (x, h); row bins from (y, w) — axis swap per reference.
    const float hq = h * 0.25f;   // exact h/4
    const float wq = w * 0.25f;
    const int c0 = max(__float2int_rn(x + (float)ix       * hq), 0);
    const int c1 = min(__float2int_rn(x + (float)(ix + 1) * hq), IMG_W);
    const int r0 = max(__float2int_rn(y + (float)jy       * wq), 0);
    const int r1 = min(__float2int_rn(y + (float)(jy + 1) * wq), IMG_H);

    const float NEG = -__builtin_inff();
    float4 m0 = make_float4(NEG, NEG, NEG, NEG);
    float4 m1 = m0;

    const float* basep = img + (size_t)b * IMG_H * IMG_W * NCH + (size_t)c4 * 4;
    for (int row = r0; row < r1; ++row) {
        const float* rp = basep + (size_t)row * (IMG_W * NCH);
        int col = c0;
        // two rotating accumulators -> >=2 independent loads in flight
        for (; col + 2 <= c1; col += 2) {
            const float4 v0 = *reinterpret_cast<const float4*>(rp + (size_t)col       * NCH);
            const float4 v1 = *reinterpret_cast<const float4*>(rp + (size_t)(col + 1) * NCH);
            m0 = fmax4(m0, v0);
            m1 = fmax4(m1, v1);
        }
        if (col < c1) {
            const float4 v0 = *reinterpret_cast<const float4*>(rp + (size_t)col * NCH);
            m0 = fmax4(m0, v0);
        }
    }
    const float4 m = fmax4(m0, m1);

    float* ob = out + (size_t)br * 21 * NCH;

    // level 4: bin 5 + ix*4 + jy
    *reinterpret_cast<float4*>(ob + (size_t)(5 + ix * 4 + jy) * NCH + (size_t)c4 * 4) = m;

    // share the 4x4 grid for level-2 / level-1 reduction
    __shared__ float4 P[4][4][64];   // [ix][jy][c4], 16 KB
    P[ix][jy][c4] = m;
    __syncthreads();

    if (tid < 256) {
        // level 2: 4 bins x 64 c4-groups. bin (i,j) = max of level4 (2i..2i+1, 2j..2j+1)
        const int cc = tid & 63;
        const int bb = tid >> 6;      // 0..3
        const int i  = bb >> 1, j = bb & 1;
        const float4 v = fmax4(
            fmax4(P[2 * i][2 * j][cc],     P[2 * i][2 * j + 1][cc]),
            fmax4(P[2 * i + 1][2 * j][cc], P[2 * i + 1][2 * j + 1][cc]));
        *reinterpret_cast<float4*>(ob + (size_t)(1 + i * 2 + j) * NCH + (size_t)cc * 4) = v;
    } else if (tid < 320) {
        // level 1: 64 c4-groups, max over all 16 level-4 bins
        const int cc = tid & 63;
        float4 v = P[0][0][cc];
#pragma unroll
        for (int i = 0; i < 4; ++i)
#pragma unroll
            for (int j = 0; j < 4; ++j)
                if (i | j) v = fmax4(v, P[i][j][cc]);
        *reinterpret_cast<float4*>(ob + (size_t)c4 * 4) = v;
    }
}

extern "C" void kernel_launch(void* const* d_in, const int* in_sizes, int n_in,
                              void* d_out, int out_size, void* d_ws, size_t ws_size,
                              hipStream_t stream) {
    const float* img  = (const float*)d_in[0];
    const float* rois = (const float*)d_in[1];
    float* out = (float*)d_out;

    const int n_rois = in_sizes[1] / 4;   // B * R = 256
    roi_pool_kernel<<<n_rois, 1024, 0, stream>>>(img, rois, out);
}